// Round 14
// baseline (192.774 us; speedup 1.0000x reference)
//
#include <hip/hip_runtime.h>
#include <hip/hip_fp16.h>
#include <math.h>

#define N    20000
#define E    200000
#define EP   220000   // E + N self loops
#define F_IN 23
#define D1   960
#define H1   8
#define C1   120
#define KPL  15       // real channels per lane
#define PC   16       // padded channels per lane
#define ROW  1024     // halves per node row (2048 B)

typedef _Float16 f16x2 __attribute__((ext_vector_type(2)));
typedef unsigned int u32x4 __attribute__((ext_vector_type(4)));

__device__ inline float fdot2(__half2 a, __half2 b, float c) {
#if __has_builtin(__builtin_amdgcn_fdot2)
  f16x2 av, bv;
  __builtin_memcpy(&av, &a, 4);
  __builtin_memcpy(&bv, &b, 4);
  return __builtin_amdgcn_fdot2(av, bv, c, false);
#else
  float2 af = __half22float2(a), bf = __half22float2(b);
  return fmaf(af.x, bf.x, fmaf(af.y, bf.y, c));
#endif
}

// packed half2 max (ROCm 7.2 lacks __hmax2) -> v_pk_max_f16
__device__ inline __half2 hmax2(__half2 a, __half2 b) {
  f16x2 av, bv;
  __builtin_memcpy(&av, &a, 4);
  __builtin_memcpy(&bv, &b, 4);
  f16x2 rv = __builtin_elementwise_max(av, bv);
  __half2 r;
  __builtin_memcpy(&r, &rv, 4);
  return r;
}

// ------- fused: transform1 (blocks 0..249) + count (250..255) + scan -------
// Transform: W in LDS fp16 (R13-proven: no register-allocator gamble),
// v_dot2_f32_f16 compute, LDS-staged output, coalesced 16B NT flush.
// Count: 6 grid-stride blocks co-resident with the 250 transform blocks
// (256 total = CU count) -> counting runs in t1's shadow. Last count block
// (dcnt ticket, R8-proven) runs the 960-thr register scan.
#define T1_BLOCKS 250
#define T1_NPB    80
#define T1_TILE   8
#define CNT_BLOCKS 6
union WU { u32x4 q[6]; __half2 h[24]; };   // h[0..11]=Wl pairs, h[12..23]=Wr
union XU { u32x4 q[3]; __half2 h[12]; };

__global__ __launch_bounds__(960)
void k_t1_count_scan(const float* __restrict__ x,
                     const float* __restrict__ W1l, const float* __restrict__ b1l,
                     const float* __restrict__ W1r, const float* __restrict__ b1r,
                     __half* __restrict__ xl1, __half* __restrict__ xr1,
                     const int* __restrict__ ei, int* __restrict__ deg,
                     int* __restrict__ dcnt,
                     int* __restrict__ off, int* __restrict__ cursor) {
  int tid = threadIdx.x;
  __shared__ union {
    struct {
      __half  wlds[960][48];       // 92160 B: [tid][0..23]=Wl, [24..47]=Wr
      __half  lbL[T1_TILE][ROW];   // 16 KB
      __half  lbR[T1_TILE][ROW];   // 16 KB
      __half2 xs2[T1_TILE][12];    // x pairs (f=2j,2j+1), pad half = 0
    } t;
    struct { int parts[960]; int wsum[16]; } sc;
  } sh;
  __shared__ bool slast;

  if (blockIdx.x >= T1_BLOCKS) {
    // ---- count section: grid-stride over EP edges ----
    for (int id = (blockIdx.x - T1_BLOCKS) * 960 + tid; id < EP;
         id += CNT_BLOCKS * 960) {
      int dst = (id < E) ? ei[E + id] : (id - E);
      atomicAdd(&deg[dst], 1);
    }
    __syncthreads();
    if (tid == 0) {
      __threadfence();
      slast = (atomicAdd(dcnt, 1) == CNT_BLOCKS - 1);
    }
    __syncthreads();
    if (!slast) return;
    __threadfence();   // acquire: make all blocks' deg visible
    // ---- scan: 960 thr x 21 elems in registers ----
    int base = tid * 21;
    int loc[21];
    int run = 0;
#pragma unroll
    for (int e = 0; e < 21; e++) {
      int i = base + e;
      int v = (i < N) ? __hip_atomic_load(&deg[i], __ATOMIC_RELAXED,
                                          __HIP_MEMORY_SCOPE_AGENT)
                      : 0;
      loc[e] = run;
      run += v;
    }
    sh.sc.parts[tid] = run;
    __syncthreads();
    int lane = tid & 63, wid = tid >> 6;   // wid in [0,15)
    int v = sh.sc.parts[tid];
    int incl = v;
#pragma unroll
    for (int d = 1; d < 64; d <<= 1) {
      int t = __shfl_up(incl, d, 64);
      if (lane >= d) incl += t;
    }
    if (lane == 63) sh.sc.wsum[wid] = incl;
    __syncthreads();
    if (tid == 0) {
      int acc = 0;
#pragma unroll
      for (int w = 0; w < 15; w++) { int t = sh.sc.wsum[w]; sh.sc.wsum[w] = acc; acc += t; }
      sh.sc.wsum[15] = acc;
    }
    __syncthreads();
    int texcl = incl - v + sh.sc.wsum[wid];
#pragma unroll
    for (int e = 0; e < 21; e++) {
      int i = base + e;
      if (i < N) { int t = texcl + loc[e]; off[i] = t; cursor[i] = t; }
    }
    if (tid == 0) off[N] = sh.sc.wsum[15];
    return;
  }

  // ---- transform ----
  int rlane = tid / 15;
  int k = tid - rlane * 15;
  int c = (rlane >> 3) * C1 + (rlane & 7) * KPL + k;   // real channel
  int pidx = rlane * PC + k;                            // permuted slot

  // W -> LDS (once per block; reads hit L2 after the first blocks)
  for (int f = 0; f < F_IN; f++) {
    sh.t.wlds[tid][f]      = __float2half(W1l[f * D1 + c]);
    sh.t.wlds[tid][24 + f] = __float2half(W1r[f * D1 + c]);
  }
  sh.t.wlds[tid][23] = __ushort_as_half((unsigned short)0);
  sh.t.wlds[tid][47] = __ushort_as_half((unsigned short)0);
  float blv = b1l[c], brv = b1r[c];

  // zero the pad slots (k==15 of each lane) in the staging buffers, once
  if (tid < 64 * T1_TILE) {
    int r = tid >> 6, l = tid & 63;
    sh.t.lbL[r][l * PC + 15] = __ushort_as_half((unsigned short)0);
    sh.t.lbR[r][l * PC + 15] = __ushort_as_half((unsigned short)0);
  }
  __syncthreads();

  int nbase = blockIdx.x * T1_NPB;
  for (int t = 0; t < T1_NPB; t += T1_TILE) {
    // stage x tile as half2 pairs
    if (tid < T1_TILE * 12) {
      int n = tid / 12, j = tid - n * 12;
      const float* xp = &x[(size_t)(nbase + t + n) * F_IN];
      float f0 = xp[2 * j];
      float f1 = (2 * j + 1 < F_IN) ? xp[2 * j + 1] : 0.f;
      sh.t.xs2[n][j] = __floats2half2_rn(f0, f1);
    }
    __syncthreads();   // xs2 staged; also orders previous tile's flush

    WU w;
    const u32x4* wp = (const u32x4*)&sh.t.wlds[tid][0];
#pragma unroll
    for (int q = 0; q < 6; q++) w.q[q] = wp[q];

#pragma unroll
    for (int n = 0; n < T1_TILE; n++) {
      XU xu;
      const u32x4* xp = (const u32x4*)&sh.t.xs2[n][0];
#pragma unroll
      for (int q = 0; q < 3; q++) xu.q[q] = xp[q];   // broadcast reads
      float al = blv, ar = brv;
#pragma unroll
      for (int j = 0; j < 12; j++) {
        al = fdot2(w.h[j],      xu.h[j], al);
        ar = fdot2(w.h[12 + j], xu.h[j], ar);
      }
      sh.t.lbL[n][pidx] = __float2half(al);
      sh.t.lbR[n][pidx] = __float2half(ar);
    }
    __syncthreads();   // lbuf complete
    // cooperative flush: 2 arrays x 8 rows x 128 x 16B, coalesced NT stores
    const u32x4* lbLu = (const u32x4*)sh.t.lbL;
    const u32x4* lbRu = (const u32x4*)sh.t.lbR;
    for (int i = tid; i < 2 * T1_TILE * 128; i += 960) {
      int arr = i >> 10;          // 0: L, 1: R  (1024 x 16B per array)
      int j = i & 1023;
      int r = j >> 7, o = j & 127;
      u32x4 val = arr ? lbRu[j] : lbLu[j];
      u32x4* dst = (u32x4*)((arr ? xr1 : xl1) + ((size_t)(nbase + t + r) << 10)) + o;
      __builtin_nontemporal_store(val, dst);
    }
  }
}

// scatter: store src node id directly
__global__ __launch_bounds__(512)
void k_scatter(const int* __restrict__ ei, int* __restrict__ cursor,
               int* __restrict__ srcs) {
  int id = blockIdx.x * 512 + threadIdx.x;
  if (id >= EP) return;
  int dst, src;
  if (id < E) { dst = ei[E + id]; src = ei[id]; }
  else        { dst = id - E;     src = id - E; }
  int pos = atomicAdd(&cursor[dst], 1);
  srcs[pos] = src;
}

// ---------------- fused layer1 aggregate + relu + layer2 transform ----------
// R6 config (best measured): 256 thr / 4 waves / 1 node per wave / depth-2
// prefetch, default launch bounds (VGPR 36, no spill). 73 us at the
// random-2KB-gather compulsory-traffic floor (222 MB FETCH).
union Rowu {
  uint4 u[2];
  __half2 h[8];
};

__global__ __launch_bounds__(256)
void k_l1agg(const int* __restrict__ off, const int* __restrict__ srcs,
             const __half* __restrict__ xl1, const __half* __restrict__ xr1,
             const float* __restrict__ att1, const float* __restrict__ bias1,
             const float* __restrict__ W2l, const float* __restrict__ b2l,
             const float* __restrict__ W2r, const float* __restrict__ b2r,
             float* __restrict__ xl2, float* __restrict__ xr2) {
  int node = blockIdx.x * 4 + (threadIdx.x >> 6);
  if (node >= N) return;
  int lane = threadIdx.x & 63;
  int cbase = (lane >> 3) * C1 + (lane & 7) * KPL;

  Rowu xr;
  {
    const uint4* rp = (const uint4*)(xr1 + ((size_t)node << 10)) + (lane << 1);
    xr.u[0] = rp[0]; xr.u[1] = rp[1];
  }
  __half2 at2[8];
#pragma unroll
  for (int j = 0; j < 7; j++)
    at2[j] = __floats2half2_rn(att1[cbase + 2 * j], att1[cbase + 2 * j + 1]);
  at2[7] = __floats2half2_rn(att1[cbase + 14], 0.f);

  const __half2 c02 = __float2half2_rn(0.2f);
  __half2 o2[8];
#pragma unroll
  for (int j = 0; j < 8; j++) o2[j] = __float2half2_rn(0.f);
  float m = -INFINITY, d = 0.f;

  int p0 = off[node], p1 = off[node + 1];
  int sA = srcs[p0];
  int sB = srcs[(p0 + 1 < p1) ? p0 + 1 : p1 - 1];
  Rowu rA, rB;
  {
    const uint4* rp = (const uint4*)(xl1 + ((size_t)sA << 10)) + (lane << 1);
    rA.u[0] = rp[0]; rA.u[1] = rp[1];
    const uint4* np = (const uint4*)(xl1 + ((size_t)sB << 10)) + (lane << 1);
    rB.u[0] = np[0]; rB.u[1] = np[1];
  }

  for (int p = p0; p < p1; p++) {
    Rowu cur = rA;
    rA = rB;
    int pn = (p + 2 < p1) ? p + 2 : p1 - 1;
    int sn = srcs[pn];
    const uint4* np = (const uint4*)(xl1 + ((size_t)sn << 10)) + (lane << 1);
    rB.u[0] = np[0]; rB.u[1] = np[1];

    float pe = 0.f;
#pragma unroll
    for (int j = 0; j < 8; j++) {
      __half2 s = __hadd2(cur.h[j], xr.h[j]);
      __half2 l = hmax2(s, __hmul2(c02, s));   // leaky = max(s, 0.2s)
      pe = fdot2(l, at2[j], pe);
    }
    pe += __shfl_xor(pe, 1, 64);
    pe += __shfl_xor(pe, 2, 64);
    pe += __shfl_xor(pe, 4, 64);
    if (pe > m) {
      float sc = __expf(m - pe);   // m=-inf first edge -> 0
      d *= sc;
      __half2 s2 = __float2half2_rn(sc);
#pragma unroll
      for (int j = 0; j < 8; j++) o2[j] = __hmul2(o2[j], s2);
      m = pe;
    }
    float w = __expf(pe - m);
    d += w;
    __half2 w2 = __float2half2_rn(w);
#pragma unroll
    for (int j = 0; j < 8; j++) o2[j] = __hfma2(w2, cur.h[j], o2[j]);
  }

  float inv = 1.f / (d + 1e-16f);
  float pl = 0.f, pr = 0.f;
#pragma unroll
  for (int j = 0; j < 8; j++) {
    float2 of = __half22float2(o2[j]);
    int k0 = 2 * j;
    float hv = fmaf(of.x, inv, bias1[cbase + k0]);
    hv = fmaxf(hv, 0.f);
    pl = fmaf(hv, W2l[cbase + k0], pl);
    pr = fmaf(hv, W2r[cbase + k0], pr);
    if (j < 7) {
      float hv2 = fmaf(of.y, inv, bias1[cbase + k0 + 1]);
      hv2 = fmaxf(hv2, 0.f);
      pl = fmaf(hv2, W2l[cbase + k0 + 1], pl);
      pr = fmaf(hv2, W2r[cbase + k0 + 1], pr);
    }
  }
#pragma unroll
  for (int dx = 1; dx < 64; dx <<= 1) {
    pl += __shfl_xor(pl, dx, 64);
    pr += __shfl_xor(pr, dx, 64);
  }
  if (lane == 0) {
    xl2[node] = pl + b2l[0];
    xr2[node] = pr + b2r[0];
  }
}

// ---------------- layer 2 aggregate ----------------
__global__ void k_l2agg(const int* __restrict__ off, const int* __restrict__ srcs,
                        const float* __restrict__ xl2, const float* __restrict__ xr2,
                        const float* __restrict__ att2, const float* __restrict__ bias2,
                        float* __restrict__ out) {
  int node = blockIdx.x * blockDim.x + threadIdx.x;
  if (node >= N) return;
  float xr = xr2[node];
  float a2 = att2[0];
  float m = -INFINITY, d = 0.f, o = 0.f;
  int p1 = off[node + 1];
  for (int p = off[node]; p < p1; p++) {
    float xl = xl2[srcs[p]];
    float s = xl + xr;
    s = fmaxf(s, 0.2f * s);
    float e = s * a2;
    if (e > m) { float sc = __expf(m - e); d *= sc; o *= sc; m = e; }
    float w = __expf(e - m);
    d += w;
    o = fmaf(w, xl, o);
  }
  out[node] = o / (d + 1e-16f) + bias2[0];
}

extern "C" void kernel_launch(void* const* d_in, const int* in_sizes, int n_in,
                              void* d_out, int out_size, void* d_ws, size_t ws_size,
                              hipStream_t stream) {
  const float* x     = (const float*)d_in[0];
  const int*   ei    = (const int*)d_in[1];
  const float* W1l   = (const float*)d_in[2];
  const float* b1l   = (const float*)d_in[3];
  const float* W1r   = (const float*)d_in[4];
  const float* b1r   = (const float*)d_in[5];
  const float* att1  = (const float*)d_in[6];
  const float* bias1 = (const float*)d_in[7];
  const float* W2l   = (const float*)d_in[8];
  const float* b2l   = (const float*)d_in[9];
  const float* W2r   = (const float*)d_in[10];
  const float* b2r   = (const float*)d_in[11];
  const float* att2  = (const float*)d_in[12];
  const float* bias2 = (const float*)d_in[13];
  float* out = (float*)d_out;

  char* ws = (char*)d_ws;
  size_t off_b = 0;
  auto alloc = [&](size_t bytes) {
    size_t cur = off_b;
    off_b += (bytes + 255) & ~(size_t)255;
    return (void*)(ws + cur);
  };
  __half* xl1 = (__half*)alloc((size_t)N * ROW * sizeof(__half));
  __half* xr1 = (__half*)alloc((size_t)N * ROW * sizeof(__half));
  int*   deg  = (int*)alloc((size_t)(N + 1) * sizeof(int));  // [N] = done-counter
  int*   offp = (int*)alloc((size_t)(N + 1) * sizeof(int));
  int*   curs = (int*)alloc((size_t)N * sizeof(int));
  int*   srcs = (int*)alloc((size_t)EP * sizeof(int));
  float* xl2  = (float*)alloc((size_t)N * sizeof(float));
  float* xr2  = (float*)alloc((size_t)N * sizeof(float));
  int*   dcnt = deg + N;
  (void)ws_size; (void)in_sizes; (void)n_in; (void)out_size;

  (void)hipMemsetAsync(deg, 0, (size_t)(N + 1) * sizeof(int), stream);

  k_t1_count_scan<<<T1_BLOCKS + CNT_BLOCKS, 960, 0, stream>>>(
      x, W1l, b1l, W1r, b1r, xl1, xr1, ei, deg, dcnt, offp, curs);

  k_scatter<<<(EP + 511) / 512, 512, 0, stream>>>(ei, curs, srcs);

  k_l1agg<<<(N + 3) / 4, 256, 0, stream>>>(
      offp, srcs, xl1, xr1, att1, bias1, W2l, b2l, W2r, b2r, xl2, xr2);

  k_l2agg<<<(N + 255) / 256, 256, 0, stream>>>(
      offp, srcs, xl2, xr2, att2, bias2, out);
}

// Round 15
// 144.628 us; speedup vs baseline: 1.3329x; 1.3329x over previous
//
#include <hip/hip_runtime.h>
#include <hip/hip_fp16.h>
#include <math.h>

#define N    20000
#define E    200000
#define EP   220000   // E + N self loops
#define F_IN 23
#define D1   960
#define H1   8
#define C1   120
#define KPL  15       // real channels per lane
#define PC   16       // padded channels per lane
#define ROW  1024     // halves per node row (2048 B)

typedef _Float16 f16x2 __attribute__((ext_vector_type(2)));
typedef unsigned int u32x4 __attribute__((ext_vector_type(4)));

__device__ inline float fdot2(__half2 a, __half2 b, float c) {
#if __has_builtin(__builtin_amdgcn_fdot2)
  f16x2 av, bv;
  __builtin_memcpy(&av, &a, 4);
  __builtin_memcpy(&bv, &b, 4);
  return __builtin_amdgcn_fdot2(av, bv, c, false);
#else
  float2 af = __half22float2(a), bf = __half22float2(b);
  return fmaf(af.x, bf.x, fmaf(af.y, bf.y, c));
#endif
}

// packed half2 max (ROCm 7.2 lacks __hmax2) -> v_pk_max_f16
__device__ inline __half2 hmax2(__half2 a, __half2 b) {
  f16x2 av, bv;
  __builtin_memcpy(&av, &a, 4);
  __builtin_memcpy(&bv, &b, 4);
  f16x2 rv = __builtin_elementwise_max(av, bv);
  __half2 r;
  __builtin_memcpy(&r, &rv, 4);
  return r;
}

// ---------------- count: deg histogram (separate: needs high occupancy) ----
__global__ __launch_bounds__(512)
void k_count(const int* __restrict__ ei, int* __restrict__ deg) {
  int id = blockIdx.x * 512 + threadIdx.x;
  if (id >= EP) return;
  int dst = (id < E) ? ei[E + id] : (id - E);
  atomicAdd(&deg[dst], 1);
}

// ------- transform1 (blocks 0..249) + scan (block 250) ---------------------
// W lives in LDS (fp16, transposed per-thread rows) — no dependence on the
// register allocator keeping 46 floats resident (R5/R9/R10/R12 all lost that
// gamble: VGPR<=64 -> ~3.5GB W reloads from L2 -> t1 pinned at 80-90us).
// Compute via v_dot2_f32_f16 on half2 pairs. Output staged in LDS, flushed
// as coalesced 16B NT stores (proven: WRITE_SIZE 86MB, no amplification).
// Scan block runs concurrently with transform blocks (251 blocks <= 256 CUs);
// deg is complete because k_count ran as the previous kernel.
// NOTE (R14 lesson): fusing count+ticket+scan INTO this kernel regressed it
// 45->100us (codegen + tail effects). Keep count separate.
#define T1_BLOCKS 250
#define T1_NPB    80
#define T1_TILE   8
union WU { u32x4 q[6]; __half2 h[24]; };   // h[0..11]=Wl pairs, h[12..23]=Wr
union XU { u32x4 q[3]; __half2 h[12]; };

__global__ __launch_bounds__(960)
void k_t1_scan(const float* __restrict__ x,
               const float* __restrict__ W1l, const float* __restrict__ b1l,
               const float* __restrict__ W1r, const float* __restrict__ b1r,
               __half* __restrict__ xl1, __half* __restrict__ xr1,
               const int* __restrict__ deg,
               int* __restrict__ off, int* __restrict__ cursor) {
  int tid = threadIdx.x;
  __shared__ union {
    struct {
      __half  wlds[960][48];       // 92160 B: [tid][0..23]=Wl, [24..47]=Wr
      __half  lbL[T1_TILE][ROW];   // 16 KB
      __half  lbR[T1_TILE][ROW];   // 16 KB
      __half2 xs2[T1_TILE][12];    // x pairs (f=2j,2j+1), pad half = 0
    } t;
    struct { int parts[960]; int wsum[16]; } sc;
  } sh;

  if (blockIdx.x >= T1_BLOCKS) {
    // ---- scan block: 960 thr x 21 elems in registers ----
    int base = tid * 21;
    int loc[21];
    int run = 0;
#pragma unroll
    for (int e = 0; e < 21; e++) {
      int i = base + e;
      int v = (i < N) ? deg[i] : 0;
      loc[e] = run;
      run += v;
    }
    sh.sc.parts[tid] = run;
    __syncthreads();
    int lane = tid & 63, wid = tid >> 6;   // wid in [0,15)
    int v = sh.sc.parts[tid];
    int incl = v;
#pragma unroll
    for (int d = 1; d < 64; d <<= 1) {
      int t = __shfl_up(incl, d, 64);
      if (lane >= d) incl += t;
    }
    if (lane == 63) sh.sc.wsum[wid] = incl;
    __syncthreads();
    if (tid == 0) {
      int acc = 0;
#pragma unroll
      for (int w = 0; w < 15; w++) { int t = sh.sc.wsum[w]; sh.sc.wsum[w] = acc; acc += t; }
      sh.sc.wsum[15] = acc;
    }
    __syncthreads();
    int texcl = incl - v + sh.sc.wsum[wid];
#pragma unroll
    for (int e = 0; e < 21; e++) {
      int i = base + e;
      if (i < N) { int t = texcl + loc[e]; off[i] = t; cursor[i] = t; }
    }
    if (tid == 0) off[N] = sh.sc.wsum[15];
    return;
  }

  // ---- transform ----
  int rlane = tid / 15;
  int k = tid - rlane * 15;
  int c = (rlane >> 3) * C1 + (rlane & 7) * KPL + k;   // real channel
  int pidx = rlane * PC + k;                            // permuted slot

  // W -> LDS (once per block; reads hit L2 after the first blocks)
  for (int f = 0; f < F_IN; f++) {
    sh.t.wlds[tid][f]      = __float2half(W1l[f * D1 + c]);
    sh.t.wlds[tid][24 + f] = __float2half(W1r[f * D1 + c]);
  }
  sh.t.wlds[tid][23] = __ushort_as_half((unsigned short)0);
  sh.t.wlds[tid][47] = __ushort_as_half((unsigned short)0);
  float blv = b1l[c], brv = b1r[c];

  // zero the pad slots (k==15 of each lane) in the staging buffers, once
  if (tid < 64 * T1_TILE) {
    int r = tid >> 6, l = tid & 63;
    sh.t.lbL[r][l * PC + 15] = __ushort_as_half((unsigned short)0);
    sh.t.lbR[r][l * PC + 15] = __ushort_as_half((unsigned short)0);
  }
  __syncthreads();

  int nbase = blockIdx.x * T1_NPB;
  for (int t = 0; t < T1_NPB; t += T1_TILE) {
    // stage x tile as half2 pairs
    if (tid < T1_TILE * 12) {
      int n = tid / 12, j = tid - n * 12;
      const float* xp = &x[(size_t)(nbase + t + n) * F_IN];
      float f0 = xp[2 * j];
      float f1 = (2 * j + 1 < F_IN) ? xp[2 * j + 1] : 0.f;
      sh.t.xs2[n][j] = __floats2half2_rn(f0, f1);
    }
    __syncthreads();   // xs2 staged; also orders previous tile's flush

    WU w;
    const u32x4* wp = (const u32x4*)&sh.t.wlds[tid][0];
#pragma unroll
    for (int q = 0; q < 6; q++) w.q[q] = wp[q];

#pragma unroll
    for (int n = 0; n < T1_TILE; n++) {
      XU xu;
      const u32x4* xp = (const u32x4*)&sh.t.xs2[n][0];
#pragma unroll
      for (int q = 0; q < 3; q++) xu.q[q] = xp[q];   // broadcast reads
      float al = blv, ar = brv;
#pragma unroll
      for (int j = 0; j < 12; j++) {
        al = fdot2(w.h[j],      xu.h[j], al);
        ar = fdot2(w.h[12 + j], xu.h[j], ar);
      }
      sh.t.lbL[n][pidx] = __float2half(al);
      sh.t.lbR[n][pidx] = __float2half(ar);
    }
    __syncthreads();   // lbuf complete
    // cooperative flush: 2 arrays x 8 rows x 128 x 16B, coalesced NT stores
    const u32x4* lbLu = (const u32x4*)sh.t.lbL;
    const u32x4* lbRu = (const u32x4*)sh.t.lbR;
    for (int i = tid; i < 2 * T1_TILE * 128; i += 960) {
      int arr = i >> 10;          // 0: L, 1: R  (1024 x 16B per array)
      int j = i & 1023;
      int r = j >> 7, o = j & 127;
      u32x4 val = arr ? lbRu[j] : lbLu[j];
      u32x4* dst = (u32x4*)((arr ? xr1 : xl1) + ((size_t)(nbase + t + r) << 10)) + o;
      __builtin_nontemporal_store(val, dst);
    }
  }
}

// scatter: store src node id directly
__global__ __launch_bounds__(512)
void k_scatter(const int* __restrict__ ei, int* __restrict__ cursor,
               int* __restrict__ srcs) {
  int id = blockIdx.x * 512 + threadIdx.x;
  if (id >= EP) return;
  int dst, src;
  if (id < E) { dst = ei[E + id]; src = ei[id]; }
  else        { dst = id - E;     src = id - E; }
  int pos = atomicAdd(&cursor[dst], 1);
  srcs[pos] = src;
}

// ---------------- fused layer1 aggregate + relu + layer2 transform ----------
// R6 config (best measured): 256 thr / 4 waves / 1 node per wave / depth-2
// prefetch, default launch bounds (VGPR 36, no spill). 73 us at the
// random-2KB-gather compulsory-traffic floor (222 MB FETCH).
union Rowu {
  uint4 u[2];
  __half2 h[8];
};

__global__ __launch_bounds__(256)
void k_l1agg(const int* __restrict__ off, const int* __restrict__ srcs,
             const __half* __restrict__ xl1, const __half* __restrict__ xr1,
             const float* __restrict__ att1, const float* __restrict__ bias1,
             const float* __restrict__ W2l, const float* __restrict__ b2l,
             const float* __restrict__ W2r, const float* __restrict__ b2r,
             float* __restrict__ xl2, float* __restrict__ xr2) {
  int node = blockIdx.x * 4 + (threadIdx.x >> 6);
  if (node >= N) return;
  int lane = threadIdx.x & 63;
  int cbase = (lane >> 3) * C1 + (lane & 7) * KPL;

  Rowu xr;
  {
    const uint4* rp = (const uint4*)(xr1 + ((size_t)node << 10)) + (lane << 1);
    xr.u[0] = rp[0]; xr.u[1] = rp[1];
  }
  __half2 at2[8];
#pragma unroll
  for (int j = 0; j < 7; j++)
    at2[j] = __floats2half2_rn(att1[cbase + 2 * j], att1[cbase + 2 * j + 1]);
  at2[7] = __floats2half2_rn(att1[cbase + 14], 0.f);

  const __half2 c02 = __float2half2_rn(0.2f);
  __half2 o2[8];
#pragma unroll
  for (int j = 0; j < 8; j++) o2[j] = __float2half2_rn(0.f);
  float m = -INFINITY, d = 0.f;

  int p0 = off[node], p1 = off[node + 1];
  int sA = srcs[p0];
  int sB = srcs[(p0 + 1 < p1) ? p0 + 1 : p1 - 1];
  Rowu rA, rB;
  {
    const uint4* rp = (const uint4*)(xl1 + ((size_t)sA << 10)) + (lane << 1);
    rA.u[0] = rp[0]; rA.u[1] = rp[1];
    const uint4* np = (const uint4*)(xl1 + ((size_t)sB << 10)) + (lane << 1);
    rB.u[0] = np[0]; rB.u[1] = np[1];
  }

  for (int p = p0; p < p1; p++) {
    Rowu cur = rA;
    rA = rB;
    int pn = (p + 2 < p1) ? p + 2 : p1 - 1;
    int sn = srcs[pn];
    const uint4* np = (const uint4*)(xl1 + ((size_t)sn << 10)) + (lane << 1);
    rB.u[0] = np[0]; rB.u[1] = np[1];

    float pe = 0.f;
#pragma unroll
    for (int j = 0; j < 8; j++) {
      __half2 s = __hadd2(cur.h[j], xr.h[j]);
      __half2 l = hmax2(s, __hmul2(c02, s));   // leaky = max(s, 0.2s)
      pe = fdot2(l, at2[j], pe);
    }
    pe += __shfl_xor(pe, 1, 64);
    pe += __shfl_xor(pe, 2, 64);
    pe += __shfl_xor(pe, 4, 64);
    if (pe > m) {
      float sc = __expf(m - pe);   // m=-inf first edge -> 0
      d *= sc;
      __half2 s2 = __float2half2_rn(sc);
#pragma unroll
      for (int j = 0; j < 8; j++) o2[j] = __hmul2(o2[j], s2);
      m = pe;
    }
    float w = __expf(pe - m);
    d += w;
    __half2 w2 = __float2half2_rn(w);
#pragma unroll
    for (int j = 0; j < 8; j++) o2[j] = __hfma2(w2, cur.h[j], o2[j]);
  }

  float inv = 1.f / (d + 1e-16f);
  float pl = 0.f, pr = 0.f;
#pragma unroll
  for (int j = 0; j < 8; j++) {
    float2 of = __half22float2(o2[j]);
    int k0 = 2 * j;
    float hv = fmaf(of.x, inv, bias1[cbase + k0]);
    hv = fmaxf(hv, 0.f);
    pl = fmaf(hv, W2l[cbase + k0], pl);
    pr = fmaf(hv, W2r[cbase + k0], pr);
    if (j < 7) {
      float hv2 = fmaf(of.y, inv, bias1[cbase + k0 + 1]);
      hv2 = fmaxf(hv2, 0.f);
      pl = fmaf(hv2, W2l[cbase + k0 + 1], pl);
      pr = fmaf(hv2, W2r[cbase + k0 + 1], pr);
    }
  }
#pragma unroll
  for (int dx = 1; dx < 64; dx <<= 1) {
    pl += __shfl_xor(pl, dx, 64);
    pr += __shfl_xor(pr, dx, 64);
  }
  if (lane == 0) {
    xl2[node] = pl + b2l[0];
    xr2[node] = pr + b2r[0];
  }
}

// ---------------- layer 2 aggregate ----------------
__global__ void k_l2agg(const int* __restrict__ off, const int* __restrict__ srcs,
                        const float* __restrict__ xl2, const float* __restrict__ xr2,
                        const float* __restrict__ att2, const float* __restrict__ bias2,
                        float* __restrict__ out) {
  int node = blockIdx.x * blockDim.x + threadIdx.x;
  if (node >= N) return;
  float xr = xr2[node];
  float a2 = att2[0];
  float m = -INFINITY, d = 0.f, o = 0.f;
  int p1 = off[node + 1];
  for (int p = off[node]; p < p1; p++) {
    float xl = xl2[srcs[p]];
    float s = xl + xr;
    s = fmaxf(s, 0.2f * s);
    float e = s * a2;
    if (e > m) { float sc = __expf(m - e); d *= sc; o *= sc; m = e; }
    float w = __expf(e - m);
    d += w;
    o = fmaf(w, xl, o);
  }
  out[node] = o / (d + 1e-16f) + bias2[0];
}

extern "C" void kernel_launch(void* const* d_in, const int* in_sizes, int n_in,
                              void* d_out, int out_size, void* d_ws, size_t ws_size,
                              hipStream_t stream) {
  const float* x     = (const float*)d_in[0];
  const int*   ei    = (const int*)d_in[1];
  const float* W1l   = (const float*)d_in[2];
  const float* b1l   = (const float*)d_in[3];
  const float* W1r   = (const float*)d_in[4];
  const float* b1r   = (const float*)d_in[5];
  const float* att1  = (const float*)d_in[6];
  const float* bias1 = (const float*)d_in[7];
  const float* W2l   = (const float*)d_in[8];
  const float* b2l   = (const float*)d_in[9];
  const float* W2r   = (const float*)d_in[10];
  const float* b2r   = (const float*)d_in[11];
  const float* att2  = (const float*)d_in[12];
  const float* bias2 = (const float*)d_in[13];
  float* out = (float*)d_out;

  char* ws = (char*)d_ws;
  size_t off_b = 0;
  auto alloc = [&](size_t bytes) {
    size_t cur = off_b;
    off_b += (bytes + 255) & ~(size_t)255;
    return (void*)(ws + cur);
  };
  __half* xl1 = (__half*)alloc((size_t)N * ROW * sizeof(__half));
  __half* xr1 = (__half*)alloc((size_t)N * ROW * sizeof(__half));
  int*   deg  = (int*)alloc((size_t)N * sizeof(int));
  int*   offp = (int*)alloc((size_t)(N + 1) * sizeof(int));
  int*   curs = (int*)alloc((size_t)N * sizeof(int));
  int*   srcs = (int*)alloc((size_t)EP * sizeof(int));
  float* xl2  = (float*)alloc((size_t)N * sizeof(float));
  float* xr2  = (float*)alloc((size_t)N * sizeof(float));
  (void)ws_size; (void)in_sizes; (void)n_in; (void)out_size;

  (void)hipMemsetAsync(deg, 0, (size_t)N * sizeof(int), stream);

  k_count<<<(EP + 511) / 512, 512, 0, stream>>>(ei, deg);

  k_t1_scan<<<T1_BLOCKS + 1, 960, 0, stream>>>(
      x, W1l, b1l, W1r, b1r, xl1, xr1, deg, offp, curs);

  k_scatter<<<(EP + 511) / 512, 512, 0, stream>>>(ei, curs, srcs);

  k_l1agg<<<(N + 3) / 4, 256, 0, stream>>>(
      offp, srcs, xl1, xr1, att1, bias1, W2l, b2l, W2r, b2r, xl2, xr2);

  k_l2agg<<<(N + 255) / 256, 256, 0, stream>>>(
      offp, srcs, xl2, xr2, att2, bias2, out);
}